// Round 16
// baseline (85.655 us; speedup 1.0000x reference)
//
#include <hip/hip_runtime.h>
#include <math.h>

#define BATCH 32
#define NN 1024
#define FF 128
#define HH 128
#define NODES 32   // nodes per block in kernel A
#define PROW 72    // padded P-tile row (bf16): spreads LDS banks

typedef __attribute__((ext_vector_type(8))) short short8v;   // 8 bf16
typedef __attribute__((ext_vector_type(4))) float f32x4;     // MFMA acc

__device__ __forceinline__ unsigned short f2bf(float f) {    // RNE f32->bf16
    unsigned u = __float_as_uint(f);
    u += 0x7fffu + ((u >> 16) & 1u);
    return (unsigned short)(u >> 16);
}

// ---------------- Kernel A: h = X@W -> g (MFMA-B-fragment-swizzled bf16);
// a_self / a_neigh scalars.  g[(batch,kc,ct,lane=kg*16+li,e)] = h[kc*32+kg*8+e][ct*16+li]
__global__ __launch_bounds__(128) void gat_hidden(
    const float* __restrict__ X,      // [B,N,F]
    const float* __restrict__ W,      // [F,H]
    const float* __restrict__ Wself,  // [H]
    const float* __restrict__ Wneigh, // [H]
    unsigned short* __restrict__ g,   // [B][32 kc][8 ct][64 lane][8] bf16
    float* __restrict__ a_self,       // [B*N]
    float* __restrict__ a_neigh)      // [B*N]
{
    __shared__ float xs[NODES][FF];      // 16 KB
    __shared__ float hs[NODES][HH + 1];  // 16.5 KB
    const int tid = threadIdx.x;
    const long base_node = (long)blockIdx.x * NODES;
    const int batch = (int)(base_node >> 10);
    const int kc = (int)((base_node & 1023) >> 5);   // 32-node chunk index

    const float4* X4 = (const float4*)(X + base_node * FF);
    float4* xs4 = (float4*)&xs[0][0];
#pragma unroll
    for (int k = 0; k < (NODES * FF) / (4 * 128); k++)
        xs4[k * 128 + tid] = X4[k * 128 + tid];
    __syncthreads();

    float acc[NODES];
#pragma unroll
    for (int n = 0; n < NODES; n++) acc[n] = 0.f;
    const int c = tid;
    for (int fq = 0; fq < FF / 4; fq++) {
        const float w0 = W[(4 * fq + 0) * HH + c];
        const float w1 = W[(4 * fq + 1) * HH + c];
        const float w2 = W[(4 * fq + 2) * HH + c];
        const float w3 = W[(4 * fq + 3) * HH + c];
#pragma unroll
        for (int n = 0; n < NODES; n++) {
            const float4 x4 = *(const float4*)&xs[n][4 * fq];
            acc[n] += x4.x * w0 + x4.y * w1 + x4.z * w2 + x4.w * w3;
        }
    }
    {
        const int ct = c >> 4, li = c & 15;
        unsigned short* gb = g + ((((size_t)batch * 32 + kc) * 8 + ct) * 64) * 8;
        union { uint4 q; unsigned short u[8]; } pk;
#pragma unroll
        for (int kg = 0; kg < 4; kg++) {
#pragma unroll
            for (int e = 0; e < 8; e++) pk.u[e] = f2bf(acc[kg * 8 + e]);
            *(uint4*)(gb + (kg * 16 + li) * 8) = pk.q;
        }
    }
#pragma unroll
    for (int n = 0; n < NODES; n++) hs[n][c] = acc[n];
    __syncthreads();

    if (tid < 2 * NODES) {
        const int n = tid & (NODES - 1);
        const float* wvp = (tid < NODES) ? Wself : Wneigh;
        float s = 0.f;
        for (int cc = 0; cc < HH; cc++) s += hs[n][cc] * wvp[cc];
        if (tid < NODES) a_self[base_node + n] = s;
        else             a_neigh[base_node + n] = s;
    }
}

// ---------------- Kernel B: fused GEMM-style P@H. Block=256thr, tile 32 rows,
// K=1024 split across wave pairs (kh = wv>>1 owns 512 cols; wave = 16 rows).
// T14 prefetch: next iter's adj loads issued BEFORE the MFMA phase.
// LDS combine across k-halves (aliased onto dead P buffers), normalize+bias
// inline, direct out store. Unnormalized exp (logits O(10), overflow-safe);
// rowsum uses the bf16-ROUNDED p (consistent with the MFMA operand).
__global__ __launch_bounds__(256) void gat_attend(
    const float* __restrict__ adj,     // [B,N,N]
    const float* __restrict__ mask,    // [B,N]
    const unsigned short* __restrict__ g, // swizzled bf16 h
    const float* __restrict__ a_self,  // [B*N]
    const float* __restrict__ a_neigh, // [B*N]
    const float* __restrict__ bvec,    // [H]
    float* __restrict__ out)           // [B,N,H]
{
    const int tid = threadIdx.x;
    const int lane = tid & 63;
    const int wv = tid >> 6;
    // 1024 blocks; XCD x owns 4 batches
    const int b = blockIdx.x;
    const int xcd = b & 7;
    const int rest = b >> 3;                 // 0..127
    const int batch = xcd * 4 + (rest >> 5);
    const int tile = rest & 31;              // 0..31
    const int r0 = batch * NN + tile * 32;   // 768 % 32 == 0: tile uniform

    if (mask[r0] == 0.f) {                   // invalid tile: zero-fill out
        float4* o4 = (float4*)(out + (size_t)r0 * HH);
        o4[tid] = make_float4(0.f, 0.f, 0.f, 0.f);
        o4[tid + 256] = make_float4(0.f, 0.f, 0.f, 0.f);
        o4[tid + 512] = make_float4(0.f, 0.f, 0.f, 0.f);
        o4[tid + 768] = make_float4(0.f, 0.f, 0.f, 0.f);
        return;
    }

    __shared__ unsigned short Pb[2][2][32 * PROW];   // [kh][buf] 18432 B
    __shared__ float rsums[32][16];                  // 2 KB
    __shared__ float rtot[32];
    f32x4* accsA = (f32x4*)&Pb[0][0][0];             // epilogue alias (8 KB)
    f32x4* accsB = accsA + 512;                      // (8 KB)

    // staging geometry: thread owns rows {srow, srow+16}, col-f4 scf4, both kh
    const int srow = tid >> 4;
    const int scf4 = tid & 15;
    const float4* ar0 = (const float4*)(adj + (size_t)(r0 + srow) * NN);
    const float4* ar1 = (const float4*)(adj + (size_t)(r0 + srow + 16) * NN);
    const float4* anp = (const float4*)(a_neigh + batch * NN);
    const float asl0 = a_self[r0 + srow];
    const float asl1 = a_self[r0 + srow + 16];
    const unsigned short* gb = g + (size_t)batch * 131072;   // 32*8*64*8

    float rsr0 = 0.f, rsr1 = 0.f;            // rowsum partials (rows srow, srow+16)
    float4 pf_an0, pf_an1, pf_00, pf_10, pf_01, pf_11;

#define LOADS(t)                                                  \
    {                                                             \
        const int o = (t) * 16 + scf4;                            \
        pf_an0 = anp[o];        pf_an1 = anp[128 + o];            \
        pf_00  = ar0[o];        pf_10  = ar1[o];                  \
        pf_01  = ar0[128 + o];  pf_11  = ar1[128 + o];            \
    }
    // exp+pack+write for one (adjf4, anf4) -> P[kh][buf] row rr
#define EW(a4, n4, aslv, rsv, kh, rr, buf)                                           \
    {                                                                                \
        union { unsigned short u[4]; uint2 q; } wq;                                  \
        float x, p;                                                                  \
        x = aslv + n4.x; p = (a4.x > 0.f) ? __expf(fmaxf(x, 0.2f * x)) : 0.f;        \
        wq.u[0] = f2bf(p); rsv += __uint_as_float((unsigned)wq.u[0] << 16);          \
        x = aslv + n4.y; p = (a4.y > 0.f) ? __expf(fmaxf(x, 0.2f * x)) : 0.f;        \
        wq.u[1] = f2bf(p); rsv += __uint_as_float((unsigned)wq.u[1] << 16);          \
        x = aslv + n4.z; p = (a4.z > 0.f) ? __expf(fmaxf(x, 0.2f * x)) : 0.f;        \
        wq.u[2] = f2bf(p); rsv += __uint_as_float((unsigned)wq.u[2] << 16);          \
        x = aslv + n4.w; p = (a4.w > 0.f) ? __expf(fmaxf(x, 0.2f * x)) : 0.f;        \
        wq.u[3] = f2bf(p); rsv += __uint_as_float((unsigned)wq.u[3] << 16);          \
        *(uint2*)&Pb[kh][buf][(rr) * PROW + scf4 * 4] = wq.q;                        \
    }
#define EXPWRITE(buf)                                   \
    {                                                   \
        EW(pf_00, pf_an0, asl0, rsr0, 0, srow, buf)     \
        EW(pf_10, pf_an0, asl1, rsr1, 0, srow + 16, buf)\
        EW(pf_01, pf_an1, asl0, rsr0, 1, srow, buf)     \
        EW(pf_11, pf_an1, asl1, rsr1, 1, srow + 16, buf)\
    }

    f32x4 acc[8];
#pragma unroll
    for (int ct = 0; ct < 8; ct++)
#pragma unroll
        for (int i = 0; i < 4; i++) acc[ct][i] = 0.f;

    // prologue
    LOADS(0)
    EXPWRITE(0)
    __syncthreads();

    const int li = lane & 15;
    const int kg8 = (lane >> 4) * 8;
    const int kh = wv >> 1;
    const int rbase = (wv & 1) * 16;

    for (int it = 0; it < 8; ++it) {
        const int cur = it & 1;
        if (it < 7) LOADS(it + 1)            // issue EARLY: hides under MFMA
        // MFMA on Pb[kh][cur]: K=64 (2 kcl of 32)
#pragma unroll
        for (int kcl = 0; kcl < 2; kcl++) {
            const short8v af = *(const short8v*)&Pb[kh][cur][(rbase + li) * PROW + kcl * 32 + kg8];
            const int kcG = kh * 16 + it * 2 + kcl;
#pragma unroll
            for (int ct = 0; ct < 8; ct++) {
                const short8v bf = *(const short8v*)(gb + ((size_t)(kcG * 8 + ct) * 64 + lane) * 8);
                acc[ct] = __builtin_amdgcn_mfma_f32_16x16x32_bf16(af, bf, acc[ct], 0, 0, 0);
            }
        }
        if (it < 7) EXPWRITE(cur ^ 1)
        __syncthreads();
    }

    // epilogue: kh1 waves dump partials into dead P buffers; rowsums reduce
    if (wv == 2) {
#pragma unroll
        for (int ct = 0; ct < 8; ct++) accsA[ct * 64 + lane] = acc[ct];
    }
    if (wv == 3) {
#pragma unroll
        for (int ct = 0; ct < 8; ct++) accsB[ct * 64 + lane] = acc[ct];
    }
    rsums[srow][scf4] = rsr0;
    rsums[srow + 16][scf4] = rsr1;
    __syncthreads();
    if (tid < 32) {
        float s = 0.f;
#pragma unroll
        for (int q = 0; q < 16; q++) s += rsums[tid][q];
        rtot[tid] = s;
    }
    __syncthreads();

    if (wv < 2) {                            // wv0: rows 0-15, wv1: rows 16-31
        const f32x4* prt = (wv == 0) ? accsA : accsB;
        float invv[4];
#pragma unroll
        for (int i = 0; i < 4; i++)
            invv[i] = 1.f / rtot[rbase + (lane >> 4) * 4 + i];
#pragma unroll
        for (int ct = 0; ct < 8; ct++) {
            const f32x4 pr = prt[ct * 64 + lane];
            const float bv = bvec[ct * 16 + li];
#pragma unroll
            for (int i = 0; i < 4; i++) {
                const int r = rbase + (lane >> 4) * 4 + i;
                out[(size_t)(r0 + r) * HH + ct * 16 + li] =
                    (acc[ct][i] + pr[i]) * invv[i] + bv;
            }
        }
    }
#undef LOADS
#undef EW
#undef EXPWRITE
}

extern "C" void kernel_launch(void* const* d_in, const int* in_sizes, int n_in,
                              void* d_out, int out_size, void* d_ws, size_t ws_size,
                              hipStream_t stream) {
    const float* X      = (const float*)d_in[0];  // M_features [B,N,F]
    const float* adj    = (const float*)d_in[1];  // M_adjacency [B,N,N]
    const float* mask   = (const float*)d_in[2];  // [B,N]
    const float* W      = (const float*)d_in[3];  // [F,H]
    const float* bvec   = (const float*)d_in[4];  // [H]
    const float* Wself  = (const float*)d_in[5];  // [H,1]
    const float* Wneigh = (const float*)d_in[6];  // [H,1]
    float* out = (float*)d_out;

    char* wsb = (char*)d_ws;
    unsigned short* g = (unsigned short*)wsb;                // 8 MB
    float* a_self  = (float*)(wsb + (size_t)BATCH * NN * HH * 2);
    float* a_neigh = a_self + (size_t)BATCH * NN;

    gat_hidden<<<(BATCH * NN) / NODES, 128, 0, stream>>>(
        X, W, Wself, Wneigh, g, a_self, a_neigh);
    gat_attend<<<1024, 256, 0, stream>>>(
        adj, mask, g, a_self, a_neigh, bvec, out);
}

// Round 17
// 70.060 us; speedup vs baseline: 1.2226x; 1.2226x over previous
//
#include <hip/hip_runtime.h>
#include <math.h>

#define BATCH 32
#define NN 1024
#define FF 128
#define HH 128
#define NODES 32   // nodes per block in kernel A
#define PROW 72    // padded P-tile row (bf16): spreads LDS banks

typedef __attribute__((ext_vector_type(8))) short short8v;   // 8 bf16
typedef __attribute__((ext_vector_type(4))) float f32x4;     // MFMA acc

__device__ __forceinline__ unsigned short f2bf(float f) {    // RNE f32->bf16
    unsigned u = __float_as_uint(f);
    u += 0x7fffu + ((u >> 16) & 1u);
    return (unsigned short)(u >> 16);
}

// ---------------- Kernel A: h = X@W -> g (MFMA-B-fragment-swizzled bf16);
// a_self / a_neigh scalars.  g[(batch,kc,ct,lane=kg*16+li,e)] = h[kc*32+kg*8+e][ct*16+li]
__global__ __launch_bounds__(128) void gat_hidden(
    const float* __restrict__ X,      // [B,N,F]
    const float* __restrict__ W,      // [F,H]
    const float* __restrict__ Wself,  // [H]
    const float* __restrict__ Wneigh, // [H]
    unsigned short* __restrict__ g,   // [B][32 kc][8 ct][64 lane][8] bf16
    float* __restrict__ a_self,       // [B*N]
    float* __restrict__ a_neigh)      // [B*N]
{
    __shared__ float xs[NODES][FF];      // 16 KB
    __shared__ float hs[NODES][HH + 1];  // 16.5 KB
    const int tid = threadIdx.x;
    const long base_node = (long)blockIdx.x * NODES;
    const int batch = (int)(base_node >> 10);
    const int kc = (int)((base_node & 1023) >> 5);   // 32-node chunk index

    const float4* X4 = (const float4*)(X + base_node * FF);
    float4* xs4 = (float4*)&xs[0][0];
#pragma unroll
    for (int k = 0; k < (NODES * FF) / (4 * 128); k++)
        xs4[k * 128 + tid] = X4[k * 128 + tid];
    __syncthreads();

    float acc[NODES];
#pragma unroll
    for (int n = 0; n < NODES; n++) acc[n] = 0.f;
    const int c = tid;
    for (int fq = 0; fq < FF / 4; fq++) {
        const float w0 = W[(4 * fq + 0) * HH + c];
        const float w1 = W[(4 * fq + 1) * HH + c];
        const float w2 = W[(4 * fq + 2) * HH + c];
        const float w3 = W[(4 * fq + 3) * HH + c];
#pragma unroll
        for (int n = 0; n < NODES; n++) {
            const float4 x4 = *(const float4*)&xs[n][4 * fq];
            acc[n] += x4.x * w0 + x4.y * w1 + x4.z * w2 + x4.w * w3;
        }
    }
    {
        const int ct = c >> 4, li = c & 15;
        unsigned short* gb = g + ((((size_t)batch * 32 + kc) * 8 + ct) * 64) * 8;
        union { uint4 q; unsigned short u[8]; } pk;
#pragma unroll
        for (int kg = 0; kg < 4; kg++) {
#pragma unroll
            for (int e = 0; e < 8; e++) pk.u[e] = f2bf(acc[kg * 8 + e]);
            *(uint4*)(gb + (kg * 16 + li) * 8) = pk.q;
        }
    }
#pragma unroll
    for (int n = 0; n < NODES; n++) hs[n][c] = acc[n];
    __syncthreads();

    if (tid < 2 * NODES) {
        const int n = tid & (NODES - 1);
        const float* wvp = (tid < NODES) ? Wself : Wneigh;
        float s = 0.f;
        for (int cc = 0; cc < HH; cc++) s += hs[n][cc] * wvp[cc];
        if (tid < NODES) a_self[base_node + n] = s;
        else             a_neigh[base_node + n] = s;
    }
}

// ---------------- Kernel B: GEMM-style P@H (R15 structure, 2x blocks).
// Block=256thr, tile 32 rows x K512 chunk -> 2048 blocks (8/CU).
// Wave quadrant: rows (wv&1)*16, ct group (wv>>1)*4 -> acc[4], 8 B-loads/iter.
// Staging identical pattern to R15 (MFMA then stage(it+1) then barrier).
__global__ __launch_bounds__(256) void gat_attend(
    const float* __restrict__ adj,     // [B,N,N]
    const float* __restrict__ mask,    // [B,N]
    const unsigned short* __restrict__ g, // swizzled bf16 h
    const float* __restrict__ a_self,  // [B*N]
    const float* __restrict__ a_neigh, // [B*N]
    float* __restrict__ part0, float* __restrict__ part1,
    float* __restrict__ rs0, float* __restrict__ rs1)
{
    const int tid = threadIdx.x;
    const int lane = tid & 63;
    const int wv = tid >> 6;
    // 2048 blocks; XCD x owns 4 batches
    const int b = blockIdx.x;
    const int xcd = b & 7;
    const int rest = b >> 3;                 // 0..255
    const int batch = xcd * 4 + (rest >> 6);
    const int idx = rest & 63;
    const int tile = idx >> 1;               // 0..31 (32-row tiles)
    const int chunk = idx & 1;
    const int r0 = batch * NN + tile * 32;   // 768 % 32 == 0: tile uniform

    if (mask[r0] == 0.f) return;             // combine zero-fills masked rows

    __shared__ unsigned short P[2][32 * PROW];   // 9216 B
    __shared__ float rsums[32][16];              // 2 KB

    const int k0c = chunk * 512;
    // staging: thread owns rows {srow, srow+16}, col-f4 scf4
    const int srow = tid >> 4;               // 0..15
    const int scf4 = tid & 15;
    const float4* ar0 = (const float4*)(adj + (size_t)(r0 + srow) * NN + k0c);
    const float4* ar1 = (const float4*)(adj + (size_t)(r0 + srow + 16) * NN + k0c);
    const float4* anp = (const float4*)(a_neigh + batch * NN + k0c);
    const float asl0 = a_self[r0 + srow];
    const float asl1 = a_self[r0 + srow + 16];
    const unsigned short* gb = g + (size_t)batch * 131072;   // 32*8*64*8

    float rsr0 = 0.f, rsr1 = 0.f;

    // exp+pack+write one (adjf4, anf4) -> P[buf] row rr
#define EW(a4, n4, aslv, rsv, rr, buf)                                               \
    {                                                                                \
        union { unsigned short u[4]; uint2 q; } wq;                                  \
        float x, p;                                                                  \
        x = aslv + n4.x; p = (a4.x > 0.f) ? __expf(fmaxf(x, 0.2f * x)) : 0.f;        \
        wq.u[0] = f2bf(p); rsv += __uint_as_float((unsigned)wq.u[0] << 16);          \
        x = aslv + n4.y; p = (a4.y > 0.f) ? __expf(fmaxf(x, 0.2f * x)) : 0.f;        \
        wq.u[1] = f2bf(p); rsv += __uint_as_float((unsigned)wq.u[1] << 16);          \
        x = aslv + n4.z; p = (a4.z > 0.f) ? __expf(fmaxf(x, 0.2f * x)) : 0.f;        \
        wq.u[2] = f2bf(p); rsv += __uint_as_float((unsigned)wq.u[2] << 16);          \
        x = aslv + n4.w; p = (a4.w > 0.f) ? __expf(fmaxf(x, 0.2f * x)) : 0.f;        \
        wq.u[3] = f2bf(p); rsv += __uint_as_float((unsigned)wq.u[3] << 16);          \
        *(uint2*)&P[buf][(rr) * PROW + scf4 * 4] = wq.q;                             \
    }
#define STAGE(t, buf)                                 \
    {                                                 \
        const int o = (t) * 16 + scf4;                \
        const float4 an4 = anp[o];                    \
        const float4 a0 = ar0[o];                     \
        const float4 a1 = ar1[o];                     \
        EW(a0, an4, asl0, rsr0, srow, buf)            \
        EW(a1, an4, asl1, rsr1, srow + 16, buf)       \
    }

    f32x4 acc[4];
#pragma unroll
    for (int ct = 0; ct < 4; ct++)
#pragma unroll
        for (int i = 0; i < 4; i++) acc[ct][i] = 0.f;

    STAGE(0, 0)
    __syncthreads();

    const int li = lane & 15;
    const int kg8 = (lane >> 4) * 8;
    const int rbase = (wv & 1) * 16;         // wave's row half
    const int cg = (wv >> 1) * 4;            // wave's ct group

    for (int it = 0; it < 8; ++it) {
        const int cur = it & 1;
#pragma unroll
        for (int kcl = 0; kcl < 2; kcl++) {
            const short8v af = *(const short8v*)&P[cur][(rbase + li) * PROW + kcl * 32 + kg8];
            const int kcG = chunk * 16 + it * 2 + kcl;
#pragma unroll
            for (int ctl = 0; ctl < 4; ctl++) {
                const short8v bf = *(const short8v*)(gb + ((size_t)(kcG * 8 + cg + ctl) * 64 + lane) * 8);
                acc[ctl] = __builtin_amdgcn_mfma_f32_16x16x32_bf16(af, bf, acc[ctl], 0, 0, 0);
            }
        }
        if (it < 7) STAGE(it + 1, cur ^ 1)
        __syncthreads();
    }

    // rowsums: thread partials -> LDS -> per-row total
    rsums[srow][scf4] = rsr0;
    rsums[srow + 16][scf4] = rsr1;
    __syncthreads();
    float* rsP = chunk ? rs1 : rs0;
    if (tid < 32) {
        float s = 0.f;
#pragma unroll
        for (int q = 0; q < 16; q++) s += rsums[tid][q];
        rsP[r0 + tid] = s;
    }

    // partial D: row = rbase + (lane>>4)*4+i, col = (cg+ctl)*16+li
    float* pP = chunk ? part1 : part0;
#pragma unroll
    for (int ctl = 0; ctl < 4; ctl++)
#pragma unroll
        for (int i = 0; i < 4; i++) {
            const int r = rbase + (lane >> 4) * 4 + i;
            pP[(size_t)(r0 + r) * HH + (cg + ctl) * 16 + li] = acc[ctl][i];
        }
#undef EW
#undef STAGE
}

// ---------------- Kernel C: combine partials, normalize, bias, mask.
// XCD-aligned grid: same batch->XCD mapping as attend so partials are L2-hot.
__global__ __launch_bounds__(256) void gat_combine(
    const float* __restrict__ mask,
    const float* __restrict__ part0, const float* __restrict__ part1,
    const float* __restrict__ rs0, const float* __restrict__ rs1,
    const float* __restrict__ bvec,
    float* __restrict__ out)
{
    const int t = threadIdx.x;
    const int b = blockIdx.x;                 // 4096 blocks
    const int xcd = b & 7;
    const int rest = b >> 3;                  // 0..511
    const int batch = xcd * 4 + (rest >> 7);
    const int rowi = (rest & 127) * 8 + (t >> 5);
    const int row = batch * NN + rowi;
    const int c4 = (t & 31) * 4;
    const size_t o = (size_t)row * HH + c4;

    if (mask[row] == 0.f) {
        *(float4*)(out + o) = make_float4(0.f, 0.f, 0.f, 0.f);
        return;
    }
    const float4 a = *(const float4*)(part0 + o);
    const float4 bq = *(const float4*)(part1 + o);
    const float inv = 1.f / (rs0[row] + rs1[row]);
    const float4 bv = *(const float4*)(bvec + c4);
    float4 r;
    r.x = (a.x + bq.x) * inv + bv.x;
    r.y = (a.y + bq.y) * inv + bv.y;
    r.z = (a.z + bq.z) * inv + bv.z;
    r.w = (a.w + bq.w) * inv + bv.w;
    *(float4*)(out + o) = r;
}

extern "C" void kernel_launch(void* const* d_in, const int* in_sizes, int n_in,
                              void* d_out, int out_size, void* d_ws, size_t ws_size,
                              hipStream_t stream) {
    const float* X      = (const float*)d_in[0];  // M_features [B,N,F]
    const float* adj    = (const float*)d_in[1];  // M_adjacency [B,N,N]
    const float* mask   = (const float*)d_in[2];  // [B,N]
    const float* W      = (const float*)d_in[3];  // [F,H]
    const float* bvec   = (const float*)d_in[4];  // [H]
    const float* Wself  = (const float*)d_in[5];  // [H,1]
    const float* Wneigh = (const float*)d_in[6];  // [H,1]
    float* out = (float*)d_out;

    char* wsb = (char*)d_ws;
    unsigned short* g = (unsigned short*)wsb;
    const size_t GSZ = (size_t)BATCH * NN * HH * 2;          // 8 MB
    float* a_self  = (float*)(wsb + GSZ);
    float* a_neigh = a_self + (size_t)BATCH * NN;
    float* rs0     = a_neigh + (size_t)BATCH * NN;
    float* rs1     = rs0 + (size_t)BATCH * NN;
    float* part0   = rs1 + (size_t)BATCH * NN;
    float* part1   = part0 + (size_t)BATCH * NN * HH;

    gat_hidden<<<(BATCH * NN) / NODES, 128, 0, stream>>>(
        X, W, Wself, Wneigh, g, a_self, a_neigh);
    gat_attend<<<2048, 256, 0, stream>>>(
        adj, mask, g, a_self, a_neigh, part0, part1, rs0, rs1);
    gat_combine<<<4096, 256, 0, stream>>>(
        mask, part0, part1, rs0, rs1, bvec, out);
}

// Round 18
// 69.853 us; speedup vs baseline: 1.2262x; 1.0030x over previous
//
#include <hip/hip_runtime.h>
#include <math.h>

#define BATCH 32
#define NN 1024
#define FF 128
#define HH 128
#define NODES 32   // nodes per block in kernel A
#define PROW 72    // padded P-tile row (bf16): spreads LDS banks

typedef __attribute__((ext_vector_type(8))) short short8v;   // 8 bf16
typedef __attribute__((ext_vector_type(4))) float f32x4;     // MFMA acc

__device__ __forceinline__ unsigned short f2bf(float f) {    // RNE f32->bf16
    unsigned u = __float_as_uint(f);
    u += 0x7fffu + ((u >> 16) & 1u);
    return (unsigned short)(u >> 16);
}

// ---------------- Kernel A: h = X@W -> g (MFMA-B-fragment-swizzled bf16);
// a_self / a_neigh scalars.  g[(batch,kc,ct,lane=kg*16+li,e)] = h[kc*32+kg*8+e][ct*16+li]
__global__ __launch_bounds__(128) void gat_hidden(
    const float* __restrict__ X,      // [B,N,F]
    const float* __restrict__ W,      // [F,H]
    const float* __restrict__ Wself,  // [H]
    const float* __restrict__ Wneigh, // [H]
    unsigned short* __restrict__ g,   // [B][32 kc][8 ct][64 lane][8] bf16
    float* __restrict__ a_self,       // [B*N]
    float* __restrict__ a_neigh)      // [B*N]
{
    __shared__ float xs[NODES][FF];      // 16 KB
    __shared__ float hs[NODES][HH + 1];  // 16.5 KB
    const int tid = threadIdx.x;
    const long base_node = (long)blockIdx.x * NODES;
    const int batch = (int)(base_node >> 10);
    const int kc = (int)((base_node & 1023) >> 5);   // 32-node chunk index

    const float4* X4 = (const float4*)(X + base_node * FF);
    float4* xs4 = (float4*)&xs[0][0];
#pragma unroll
    for (int k = 0; k < (NODES * FF) / (4 * 128); k++)
        xs4[k * 128 + tid] = X4[k * 128 + tid];
    __syncthreads();

    float acc[NODES];
#pragma unroll
    for (int n = 0; n < NODES; n++) acc[n] = 0.f;
    const int c = tid;
    for (int fq = 0; fq < FF / 4; fq++) {
        const float w0 = W[(4 * fq + 0) * HH + c];
        const float w1 = W[(4 * fq + 1) * HH + c];
        const float w2 = W[(4 * fq + 2) * HH + c];
        const float w3 = W[(4 * fq + 3) * HH + c];
#pragma unroll
        for (int n = 0; n < NODES; n++) {
            const float4 x4 = *(const float4*)&xs[n][4 * fq];
            acc[n] += x4.x * w0 + x4.y * w1 + x4.z * w2 + x4.w * w3;
        }
    }
    {
        const int ct = c >> 4, li = c & 15;
        unsigned short* gb = g + ((((size_t)batch * 32 + kc) * 8 + ct) * 64) * 8;
        union { uint4 q; unsigned short u[8]; } pk;
#pragma unroll
        for (int kg = 0; kg < 4; kg++) {
#pragma unroll
            for (int e = 0; e < 8; e++) pk.u[e] = f2bf(acc[kg * 8 + e]);
            *(uint4*)(gb + (kg * 16 + li) * 8) = pk.q;
        }
    }
#pragma unroll
    for (int n = 0; n < NODES; n++) hs[n][c] = acc[n];
    __syncthreads();

    if (tid < 2 * NODES) {
        const int n = tid & (NODES - 1);
        const float* wvp = (tid < NODES) ? Wself : Wneigh;
        float s = 0.f;
        for (int cc = 0; cc < HH; cc++) s += hs[n][cc] * wvp[cc];
        if (tid < NODES) a_self[base_node + n] = s;
        else             a_neigh[base_node + n] = s;
    }
}

// ---------------- Kernel B: GEMM-style P@H (R17 geometry + T14 stage split).
// Block=256thr, tile 32 rows x K512 chunk -> 2048 blocks.
// Wave quadrant: rows (wv&1)*16, ct group (wv>>1)*4 -> acc[4], 8 B-loads/iter.
// T14: next iter's adj/a_neigh loads are ISSUED before the MFMA phase and
// CONSUMED (exp+pack+ds_write) after it -> stage latency hides under MFMA.
__global__ __launch_bounds__(256) void gat_attend(
    const float* __restrict__ adj,     // [B,N,N]
    const float* __restrict__ mask,    // [B,N]
    const unsigned short* __restrict__ g, // swizzled bf16 h
    const float* __restrict__ a_self,  // [B*N]
    const float* __restrict__ a_neigh, // [B*N]
    float* __restrict__ part0, float* __restrict__ part1,
    float* __restrict__ rs0, float* __restrict__ rs1)
{
    const int tid = threadIdx.x;
    const int lane = tid & 63;
    const int wv = tid >> 6;
    // 2048 blocks; XCD x owns 4 batches
    const int b = blockIdx.x;
    const int xcd = b & 7;
    const int rest = b >> 3;                 // 0..255
    const int batch = xcd * 4 + (rest >> 6);
    const int idx = rest & 63;
    const int tile = idx >> 1;               // 0..31 (32-row tiles)
    const int chunk = idx & 1;
    const int r0 = batch * NN + tile * 32;   // 768 % 32 == 0: tile uniform

    if (mask[r0] == 0.f) return;             // combine zero-fills masked rows

    __shared__ unsigned short P[2][32 * PROW];   // 9216 B
    __shared__ float rsums[32][16];              // 2 KB

    const int k0c = chunk * 512;
    // staging: thread owns rows {srow, srow+16}, col-f4 scf4
    const int srow = tid >> 4;               // 0..15
    const int scf4 = tid & 15;
    const float4* ar0 = (const float4*)(adj + (size_t)(r0 + srow) * NN + k0c);
    const float4* ar1 = (const float4*)(adj + (size_t)(r0 + srow + 16) * NN + k0c);
    const float4* anp = (const float4*)(a_neigh + batch * NN + k0c);
    const float asl0 = a_self[r0 + srow];
    const float asl1 = a_self[r0 + srow + 16];
    const unsigned short* gb = g + (size_t)batch * 131072;   // 32*8*64*8

    float rsr0 = 0.f, rsr1 = 0.f;
    float4 pf_an, pf_a0, pf_a1;              // in-flight stage registers (T14)

#define LOADS(t)                                      \
    {                                                 \
        const int o = (t) * 16 + scf4;                \
        pf_an = anp[o];                               \
        pf_a0 = ar0[o];                               \
        pf_a1 = ar1[o];                               \
    }
    // exp+pack+write one (adjf4, anf4) -> P[buf] row rr
#define EW(a4, n4, aslv, rsv, rr, buf)                                               \
    {                                                                                \
        union { unsigned short u[4]; uint2 q; } wq;                                  \
        float x, p;                                                                  \
        x = aslv + n4.x; p = (a4.x > 0.f) ? __expf(fmaxf(x, 0.2f * x)) : 0.f;        \
        wq.u[0] = f2bf(p); rsv += __uint_as_float((unsigned)wq.u[0] << 16);          \
        x = aslv + n4.y; p = (a4.y > 0.f) ? __expf(fmaxf(x, 0.2f * x)) : 0.f;        \
        wq.u[1] = f2bf(p); rsv += __uint_as_float((unsigned)wq.u[1] << 16);          \
        x = aslv + n4.z; p = (a4.z > 0.f) ? __expf(fmaxf(x, 0.2f * x)) : 0.f;        \
        wq.u[2] = f2bf(p); rsv += __uint_as_float((unsigned)wq.u[2] << 16);          \
        x = aslv + n4.w; p = (a4.w > 0.f) ? __expf(fmaxf(x, 0.2f * x)) : 0.f;        \
        wq.u[3] = f2bf(p); rsv += __uint_as_float((unsigned)wq.u[3] << 16);          \
        *(uint2*)&P[buf][(rr) * PROW + scf4 * 4] = wq.q;                             \
    }
#define EXPWRITE(buf)                                 \
    {                                                 \
        EW(pf_a0, pf_an, asl0, rsr0, srow, buf)       \
        EW(pf_a1, pf_an, asl1, rsr1, srow + 16, buf)  \
    }

    f32x4 acc[4];
#pragma unroll
    for (int ct = 0; ct < 4; ct++)
#pragma unroll
        for (int i = 0; i < 4; i++) acc[ct][i] = 0.f;

    // prologue: stage iter 0
    LOADS(0)
    EXPWRITE(0)
    __syncthreads();

    const int li = lane & 15;
    const int kg8 = (lane >> 4) * 8;
    const int rbase = (wv & 1) * 16;         // wave's row half
    const int cg = (wv >> 1) * 4;            // wave's ct group

    for (int it = 0; it < 8; ++it) {
        const int cur = it & 1;
        if (it < 7) LOADS(it + 1)            // T14: issue early, consume late
#pragma unroll
        for (int kcl = 0; kcl < 2; kcl++) {
            const short8v af = *(const short8v*)&P[cur][(rbase + li) * PROW + kcl * 32 + kg8];
            const int kcG = chunk * 16 + it * 2 + kcl;
#pragma unroll
            for (int ctl = 0; ctl < 4; ctl++) {
                const short8v bf = *(const short8v*)(gb + ((size_t)(kcG * 8 + cg + ctl) * 64 + lane) * 8);
                acc[ctl] = __builtin_amdgcn_mfma_f32_16x16x32_bf16(af, bf, acc[ctl], 0, 0, 0);
            }
        }
        if (it < 7) EXPWRITE(cur ^ 1)        // stage latency hidden under MFMA
        __syncthreads();
    }

    // rowsums: thread partials -> LDS -> per-row total
    rsums[srow][scf4] = rsr0;
    rsums[srow + 16][scf4] = rsr1;
    __syncthreads();
    float* rsP = chunk ? rs1 : rs0;
    if (tid < 32) {
        float s = 0.f;
#pragma unroll
        for (int q = 0; q < 16; q++) s += rsums[tid][q];
        rsP[r0 + tid] = s;
    }

    // partial D: row = rbase + (lane>>4)*4+i, col = (cg+ctl)*16+li
    float* pP = chunk ? part1 : part0;
#pragma unroll
    for (int ctl = 0; ctl < 4; ctl++)
#pragma unroll
        for (int i = 0; i < 4; i++) {
            const int r = rbase + (lane >> 4) * 4 + i;
            pP[(size_t)(r0 + r) * HH + (cg + ctl) * 16 + li] = acc[ctl][i];
        }
#undef EW
#undef STAGE
#undef LOADS
#undef EXPWRITE
}

// ---------------- Kernel C: combine partials, normalize, bias, mask.
// XCD-aligned grid: same batch->XCD mapping as attend so partials are L2-hot.
__global__ __launch_bounds__(256) void gat_combine(
    const float* __restrict__ mask,
    const float* __restrict__ part0, const float* __restrict__ part1,
    const float* __restrict__ rs0, const float* __restrict__ rs1,
    const float* __restrict__ bvec,
    float* __restrict__ out)
{
    const int t = threadIdx.x;
    const int b = blockIdx.x;                 // 4096 blocks
    const int xcd = b & 7;
    const int rest = b >> 3;                  // 0..511
    const int batch = xcd * 4 + (rest >> 7);
    const int rowi = (rest & 127) * 8 + (t >> 5);
    const int row = batch * NN + rowi;
    const int c4 = (t & 31) * 4;
    const size_t o = (size_t)row * HH + c4;

    if (mask[row] == 0.f) {
        *(float4*)(out + o) = make_float4(0.f, 0.f, 0.f, 0.f);
        return;
    }
    const float4 a = *(const float4*)(part0 + o);
    const float4 bq = *(const float4*)(part1 + o);
    const float inv = 1.f / (rs0[row] + rs1[row]);
    const float4 bv = *(const float4*)(bvec + c4);
    float4 r;
    r.x = (a.x + bq.x) * inv + bv.x;
    r.y = (a.y + bq.y) * inv + bv.y;
    r.z = (a.z + bq.z) * inv + bv.z;
    r.w = (a.w + bq.w) * inv + bv.w;
    *(float4*)(out + o) = r;
}

extern "C" void kernel_launch(void* const* d_in, const int* in_sizes, int n_in,
                              void* d_out, int out_size, void* d_ws, size_t ws_size,
                              hipStream_t stream) {
    const float* X      = (const float*)d_in[0];  // M_features [B,N,F]
    const float* adj    = (const float*)d_in[1];  // M_adjacency [B,N,N]
    const float* mask   = (const float*)d_in[2];  // [B,N]
    const float* W      = (const float*)d_in[3];  // [F,H]
    const float* bvec   = (const float*)d_in[4];  // [H]
    const float* Wself  = (const float*)d_in[5];  // [H,1]
    const float* Wneigh = (const float*)d_in[6];  // [H,1]
    float* out = (float*)d_out;

    char* wsb = (char*)d_ws;
    unsigned short* g = (unsigned short*)wsb;
    const size_t GSZ = (size_t)BATCH * NN * HH * 2;          // 8 MB
    float* a_self  = (float*)(wsb + GSZ);
    float* a_neigh = a_self + (size_t)BATCH * NN;
    float* rs0     = a_neigh + (size_t)BATCH * NN;
    float* rs1     = rs0 + (size_t)BATCH * NN;
    float* part0   = rs1 + (size_t)BATCH * NN;
    float* part1   = part0 + (size_t)BATCH * NN * HH;

    gat_hidden<<<(BATCH * NN) / NODES, 128, 0, stream>>>(
        X, W, Wself, Wneigh, g, a_self, a_neigh);
    gat_attend<<<2048, 256, 0, stream>>>(
        adj, mask, g, a_self, a_neigh, part0, part1, rs0, rs1);
    gat_combine<<<4096, 256, 0, stream>>>(
        mask, part0, part1, rs0, rs1, bvec, out);
}

// Round 19
// 60.472 us; speedup vs baseline: 1.4164x; 1.1551x over previous
//
#include <hip/hip_runtime.h>
#include <math.h>

#define BATCH 32
#define NN 1024
#define FF 128
#define HH 128
#define NODES 32   // nodes per block in kernel A
#define PROW 72    // padded P-tile row (bf16): spreads LDS banks

typedef __attribute__((ext_vector_type(8))) short short8v;   // 8 bf16
typedef __attribute__((ext_vector_type(4))) float f32x4;     // MFMA acc

__device__ __forceinline__ unsigned short f2bf(float f) {    // RNE f32->bf16
    unsigned u = __float_as_uint(f);
    u += 0x7fffu + ((u >> 16) & 1u);
    return (unsigned short)(u >> 16);
}

// ---------------- Kernel A: h = X@W -> g (MFMA-B-fragment-swizzled bf16);
// a_self / a_neigh scalars.  g[(batch,kc,ct,lane=kg*16+li,e)] = h[kc*32+kg*8+e][ct*16+li]
__global__ __launch_bounds__(128) void gat_hidden(
    const float* __restrict__ X,      // [B,N,F]
    const float* __restrict__ W,      // [F,H]
    const float* __restrict__ Wself,  // [H]
    const float* __restrict__ Wneigh, // [H]
    unsigned short* __restrict__ g,   // [B][32 kc][8 ct][64 lane][8] bf16
    float* __restrict__ a_self,       // [B*N]
    float* __restrict__ a_neigh)      // [B*N]
{
    __shared__ float xs[NODES][FF];      // 16 KB
    __shared__ float hs[NODES][HH + 1];  // 16.5 KB
    const int tid = threadIdx.x;
    const long base_node = (long)blockIdx.x * NODES;
    const int batch = (int)(base_node >> 10);
    const int kc = (int)((base_node & 1023) >> 5);   // 32-node chunk index

    const float4* X4 = (const float4*)(X + base_node * FF);
    float4* xs4 = (float4*)&xs[0][0];
#pragma unroll
    for (int k = 0; k < (NODES * FF) / (4 * 128); k++)
        xs4[k * 128 + tid] = X4[k * 128 + tid];
    __syncthreads();

    float acc[NODES];
#pragma unroll
    for (int n = 0; n < NODES; n++) acc[n] = 0.f;
    const int c = tid;
    for (int fq = 0; fq < FF / 4; fq++) {
        const float w0 = W[(4 * fq + 0) * HH + c];
        const float w1 = W[(4 * fq + 1) * HH + c];
        const float w2 = W[(4 * fq + 2) * HH + c];
        const float w3 = W[(4 * fq + 3) * HH + c];
#pragma unroll
        for (int n = 0; n < NODES; n++) {
            const float4 x4 = *(const float4*)&xs[n][4 * fq];
            acc[n] += x4.x * w0 + x4.y * w1 + x4.z * w2 + x4.w * w3;
        }
    }
    {
        const int ct = c >> 4, li = c & 15;
        unsigned short* gb = g + ((((size_t)batch * 32 + kc) * 8 + ct) * 64) * 8;
        union { uint4 q; unsigned short u[8]; } pk;
#pragma unroll
        for (int kg = 0; kg < 4; kg++) {
#pragma unroll
            for (int e = 0; e < 8; e++) pk.u[e] = f2bf(acc[kg * 8 + e]);
            *(uint4*)(gb + (kg * 16 + li) * 8) = pk.q;
        }
    }
#pragma unroll
    for (int n = 0; n < NODES; n++) hs[n][c] = acc[n];
    __syncthreads();

    if (tid < 2 * NODES) {
        const int n = tid & (NODES - 1);
        const float* wvp = (tid < NODES) ? Wself : Wneigh;
        float s = 0.f;
        for (int cc = 0; cc < HH; cc++) s += hs[n][cc] * wvp[cc];
        if (tid < NODES) a_self[base_node + n] = s;
        else             a_neigh[base_node + n] = s;
    }
}

// ---------------- Kernel B: fused GEMM-style P@H, FULL K in-block.
// Block=256thr, tile 32 rows x K1024 (16 iters) -> 1024 blocks.
// Wave quadrant: rows (wv&1)*16, ct group (wv>>1)*4 -> acc[4] holds the
// COMPLETE output quadrant after the loop; only the rowsum is cross-wave.
// Epilogue normalizes + bias + stores out directly (no partials round-trip).
// T14: next iter's adj/a_neigh loads issued before the MFMA phase.
__global__ __launch_bounds__(256) void gat_attend(
    const float* __restrict__ adj,     // [B,N,N]
    const float* __restrict__ mask,    // [B,N]
    const unsigned short* __restrict__ g, // swizzled bf16 h
    const float* __restrict__ a_self,  // [B*N]
    const float* __restrict__ a_neigh, // [B*N]
    const float* __restrict__ bvec,    // [H]
    float* __restrict__ out)           // [B,N,H]
{
    const int tid = threadIdx.x;
    const int lane = tid & 63;
    const int wv = tid >> 6;
    // 1024 blocks; XCD x owns 4 batches
    const int b = blockIdx.x;
    const int xcd = b & 7;
    const int rest = b >> 3;                 // 0..127
    const int batch = xcd * 4 + (rest >> 5);
    const int tile = rest & 31;              // 0..31 (32-row tiles)
    const int r0 = batch * NN + tile * 32;   // 768 % 32 == 0: tile uniform

    if (mask[r0] == 0.f) {                   // invalid tile: zero-fill out
        float4* o4 = (float4*)(out + (size_t)r0 * HH);
#pragma unroll
        for (int k = 0; k < 4; k++)
            o4[k * 256 + tid] = make_float4(0.f, 0.f, 0.f, 0.f);
        return;
    }

    __shared__ unsigned short P[2][32 * PROW];   // 9216 B
    __shared__ float rsums[32][16];              // 2 KB
    __shared__ float rtot[32];

    // staging: thread owns rows {srow, srow+16}, col-f4 scf4
    const int srow = tid >> 4;               // 0..15
    const int scf4 = tid & 15;
    const float4* ar0 = (const float4*)(adj + (size_t)(r0 + srow) * NN);
    const float4* ar1 = (const float4*)(adj + (size_t)(r0 + srow + 16) * NN);
    const float4* anp = (const float4*)(a_neigh + batch * NN);
    const float asl0 = a_self[r0 + srow];
    const float asl1 = a_self[r0 + srow + 16];
    const unsigned short* gb = g + (size_t)batch * 131072;   // 32*8*64*8

    float rsr0 = 0.f, rsr1 = 0.f;
    float4 pf_an, pf_a0, pf_a1;              // in-flight stage registers (T14)

#define LOADS(t)                                      \
    {                                                 \
        const int o = (t) * 16 + scf4;                \
        pf_an = anp[o];                               \
        pf_a0 = ar0[o];                               \
        pf_a1 = ar1[o];                               \
    }
#define EW(a4, n4, aslv, rsv, rr, buf)                                               \
    {                                                                                \
        union { unsigned short u[4]; uint2 q; } wq;                                  \
        float x, p;                                                                  \
        x = aslv + n4.x; p = (a4.x > 0.f) ? __expf(fmaxf(x, 0.2f * x)) : 0.f;        \
        wq.u[0] = f2bf(p); rsv += __uint_as_float((unsigned)wq.u[0] << 16);          \
        x = aslv + n4.y; p = (a4.y > 0.f) ? __expf(fmaxf(x, 0.2f * x)) : 0.f;        \
        wq.u[1] = f2bf(p); rsv += __uint_as_float((unsigned)wq.u[1] << 16);          \
        x = aslv + n4.z; p = (a4.z > 0.f) ? __expf(fmaxf(x, 0.2f * x)) : 0.f;        \
        wq.u[2] = f2bf(p); rsv += __uint_as_float((unsigned)wq.u[2] << 16);          \
        x = aslv + n4.w; p = (a4.w > 0.f) ? __expf(fmaxf(x, 0.2f * x)) : 0.f;        \
        wq.u[3] = f2bf(p); rsv += __uint_as_float((unsigned)wq.u[3] << 16);          \
        *(uint2*)&P[buf][(rr) * PROW + scf4 * 4] = wq.q;                             \
    }
#define EXPWRITE(buf)                                 \
    {                                                 \
        EW(pf_a0, pf_an, asl0, rsr0, srow, buf)       \
        EW(pf_a1, pf_an, asl1, rsr1, srow + 16, buf)  \
    }

    f32x4 acc[4];
#pragma unroll
    for (int ct = 0; ct < 4; ct++)
#pragma unroll
        for (int i = 0; i < 4; i++) acc[ct][i] = 0.f;

    // prologue: stage iter 0
    LOADS(0)
    EXPWRITE(0)
    __syncthreads();

    const int li = lane & 15;
    const int kg8 = (lane >> 4) * 8;
    const int rbase = (wv & 1) * 16;         // wave's row half
    const int cg = (wv >> 1) * 4;            // wave's ct group

    for (int it = 0; it < 16; ++it) {
        const int cur = it & 1;
        if (it < 15) LOADS(it + 1)           // T14: issue early, consume late
#pragma unroll
        for (int kcl = 0; kcl < 2; kcl++) {
            const short8v af = *(const short8v*)&P[cur][(rbase + li) * PROW + kcl * 32 + kg8];
            const int kcG = it * 2 + kcl;
#pragma unroll
            for (int ctl = 0; ctl < 4; ctl++) {
                const short8v bf = *(const short8v*)(gb + ((size_t)(kcG * 8 + cg + ctl) * 64 + lane) * 8);
                acc[ctl] = __builtin_amdgcn_mfma_f32_16x16x32_bf16(af, bf, acc[ctl], 0, 0, 0);
            }
        }
        if (it < 15) EXPWRITE(cur ^ 1)       // stage latency hidden under MFMA
        __syncthreads();
    }

    // rowsum reduce: thread partials -> LDS -> per-row totals (32 rows)
    rsums[srow][scf4] = rsr0;
    rsums[srow + 16][scf4] = rsr1;
    __syncthreads();
    if (tid < 32) {
        float s = 0.f;
#pragma unroll
        for (int q = 0; q < 16; q++) s += rsums[tid][q];
        rtot[tid] = s;
    }
    __syncthreads();

    // epilogue: each wave owns its quadrant completely (full K accumulated)
    float invv[4];
#pragma unroll
    for (int i = 0; i < 4; i++)
        invv[i] = 1.f / rtot[rbase + (lane >> 4) * 4 + i];
#pragma unroll
    for (int ctl = 0; ctl < 4; ctl++) {
        const float bv = bvec[(cg + ctl) * 16 + li];
#pragma unroll
        for (int i = 0; i < 4; i++) {
            const int r = rbase + (lane >> 4) * 4 + i;
            out[(size_t)(r0 + r) * HH + (cg + ctl) * 16 + li] =
                acc[ctl][i] * invv[i] + bv;
        }
    }
#undef EW
#undef LOADS
#undef EXPWRITE
}

extern "C" void kernel_launch(void* const* d_in, const int* in_sizes, int n_in,
                              void* d_out, int out_size, void* d_ws, size_t ws_size,
                              hipStream_t stream) {
    const float* X      = (const float*)d_in[0];  // M_features [B,N,F]
    const float* adj    = (const float*)d_in[1];  // M_adjacency [B,N,N]
    const float* mask   = (const float*)d_in[2];  // [B,N]
    const float* W      = (const float*)d_in[3];  // [F,H]
    const float* bvec   = (const float*)d_in[4];  // [H]
    const float* Wself  = (const float*)d_in[5];  // [H,1]
    const float* Wneigh = (const float*)d_in[6];  // [H,1]
    float* out = (float*)d_out;

    char* wsb = (char*)d_ws;
    unsigned short* g = (unsigned short*)wsb;                // 8 MB
    float* a_self  = (float*)(wsb + (size_t)BATCH * NN * HH * 2);
    float* a_neigh = a_self + (size_t)BATCH * NN;

    gat_hidden<<<(BATCH * NN) / NODES, 128, 0, stream>>>(
        X, W, Wself, Wneigh, g, a_self, a_neigh);
    gat_attend<<<1024, 256, 0, stream>>>(
        adj, mask, g, a_self, a_neigh, bvec, out);
}